// Round 15
// baseline (1153.433 us; speedup 1.0000x reference)
//
#include <hip/hip_runtime.h>
#include <hip/hip_bf16.h>

#define NN 50000
#define NE 600000
#define NG 1000
#define IND 16
#define HID 128
#define DESCD 17
#define NL 3
#define BN_EPS 1e-5f
#define NB_SCAN 196  // ceil(NN/256)

typedef short s16x8 __attribute__((ext_vector_type(8)));
typedef float f32x4 __attribute__((ext_vector_type(4)));
typedef int   i32x4 __attribute__((ext_vector_type(4)));
typedef __hip_bfloat16 bfp16;
typedef __hip_bfloat162 bfp162;

__device__ __forceinline__ float b2f(short s) {
    return __uint_as_float(((unsigned int)(unsigned short)s) << 16);
}

// ---------------- CSR build (5 small dispatches; NO grid.sync) -------------
__global__ __launch_bounds__(256) void k_hist(const int* __restrict__ dst,
                                              int* __restrict__ deg) {
    int e = blockIdx.x * blockDim.x + threadIdx.x;
    if (e >= NE) return;
    atomicAdd(&deg[dst[e]], 1);
}

__global__ __launch_bounds__(256) void k_part(const int* __restrict__ deg,
                                              int* __restrict__ partials) {
    __shared__ int sh[256];
    int i = blockIdx.x * 256 + threadIdx.x;
    sh[threadIdx.x] = (i < NN) ? deg[i] : 0;
    __syncthreads();
    for (int o = 128; o > 0; o >>= 1) {
        if (threadIdx.x < o) sh[threadIdx.x] += sh[threadIdx.x + o];
        __syncthreads();
    }
    if (threadIdx.x == 0) partials[blockIdx.x] = sh[0];
}

__global__ __launch_bounds__(256) void k_scanpart(const int* __restrict__ partials,
                                                  int* __restrict__ poffs) {
    __shared__ int sh[256];
    int t = threadIdx.x;
    int v = (t < NB_SCAN) ? partials[t] : 0;
    sh[t] = v;
    __syncthreads();
    for (int o = 1; o < 256; o <<= 1) {
        int tmp = (t >= o) ? sh[t - o] : 0;
        __syncthreads();
        sh[t] += tmp;
        __syncthreads();
    }
    if (t < NB_SCAN) poffs[t] = sh[t] - v;
}

__global__ __launch_bounds__(256) void k_scatter(const int* __restrict__ deg,
                                                 const int* __restrict__ poffs,
                                                 int* __restrict__ rowptr,
                                                 int* __restrict__ cursor) {
    __shared__ int sh[256];
    int b = blockIdx.x, t = threadIdx.x;
    int i = b * 256 + t;
    int v = (i < NN) ? deg[i] : 0;
    sh[t] = v;
    __syncthreads();
    for (int o = 1; o < 256; o <<= 1) {
        int tmp = (t >= o) ? sh[t - o] : 0;
        __syncthreads();
        sh[t] += tmp;
        __syncthreads();
    }
    int excl = sh[t] - v + poffs[b];
    if (i < NN) {
        rowptr[i] = excl;
        cursor[i] = excl;
        if (i == NN - 1) rowptr[NN] = excl + v;
    }
}

__global__ __launch_bounds__(256) void k_fill(const int* __restrict__ src,
                                              const int* __restrict__ dst,
                                              int* __restrict__ cursor,
                                              int2* __restrict__ perm) {
    int e = blockIdx.x * blockDim.x + threadIdx.x;
    if (e >= NE) return;
    int pos = atomicAdd(&cursor[dst[e]], 1);
    perm[pos] = make_int2(e, src[e]);
}

// ---------------- fused proj + weight prep ----------------
__global__ __launch_bounds__(256) void k_projwprep(const float* __restrict__ x,
                                                   const float* __restrict__ Wp,
                                                   const float* __restrict__ bp,
                                                   bfp16* __restrict__ h,
                                                   const float* __restrict__ W1,
                                                   const float* __restrict__ W2,
                                                   bfp16* __restrict__ Wt,
                                                   int projBlocks) {
    if (blockIdx.x < (unsigned)projBlocks) {
        int idx = blockIdx.x * blockDim.x + threadIdx.x;
        if (idx >= NN * HID) return;
        int row = idx >> 7, col = idx & 127;
        const float* xr = x + (size_t)row * IND;
        float acc = bp[col];
#pragma unroll
        for (int k = 0; k < IND; k++) acc += xr[k] * Wp[k * HID + col];
        h[idx] = __float2bfloat16(acc);
    } else {
        int id = (blockIdx.x - projBlocks) * blockDim.x + threadIdx.x;
        if (id >= 6 * HID * HID) return;
        int m = id >> 14;
        int rem = id & 16383;
        int n = rem >> 7, k = rem & 127;
        const float* Wsrc = (m < 3) ? (W1 + (size_t)m * HID * HID)
                                    : (W2 + (size_t)(m - 3) * HID * HID);
        Wt[id] = __float2bfloat16(Wsrc[k * HID + n]);
    }
}

// ---------------- gather aggregation, 4 edges/wave, 16B/lane ---------------
// REP: instrumentation repeat count (idempotent recompute; REP=1 for prod).
template <int MODE, bool BN, int REP>
__global__ __launch_bounds__(256) void k_aggr(const bfp16* __restrict__ hz,
                                              const float* __restrict__ ea,
                                              bfp16* __restrict__ eab,
                                              const int2* __restrict__ perm,
                                              const int* __restrict__ rowptr,
                                              const float* __restrict__ stats,
                                              const float* __restrict__ gamma,
                                              const float* __restrict__ beta,
                                              bfp16* __restrict__ z) {
    int nid = (blockIdx.x * blockDim.x + threadIdx.x) >> 6;
    int lane = threadIdx.x & 63;
    if (nid >= NN) return;
    const int slot = lane >> 4;
    const int c0 = (lane & 15) << 3;

    float sc[8], sf[8];
    if (BN) {
        const float invn = 1.f / NN;
#pragma unroll
        for (int j = 0; j < 8; j++) {
            int c = c0 + j;
            float m = stats[c] * invn;
            float v = stats[128 + c] * invn - m * m;
            sc[j] = rsqrtf(v + BN_EPS) * gamma[c];
            sf[j] = beta[c] - m * sc[j];
        }
    }

    const int beg = rowptr[nid], end = rowptr[nid + 1];

    for (int rep = 0; rep < REP; ++rep) {
        float acc[8];
#pragma unroll
        for (int j = 0; j < 8; j++) acc[j] = 0.f;

        auto body = [&](int i) {
            int2 pr = perm[i];
            float a[8];
            if (MODE == 1) {
                f32x4 a0 = __builtin_nontemporal_load(
                    (const f32x4*)&ea[(size_t)pr.x * HID + c0]);
                f32x4 a1 = __builtin_nontemporal_load(
                    (const f32x4*)&ea[(size_t)pr.x * HID + c0 + 4]);
                a[0] = a0.x; a[1] = a0.y; a[2] = a0.z; a[3] = a0.w;
                a[4] = a1.x; a[5] = a1.y; a[6] = a1.z; a[7] = a1.w;
                bfp162 p0 = __float22bfloat162_rn(make_float2(a[0], a[1]));
                bfp162 p1 = __float22bfloat162_rn(make_float2(a[2], a[3]));
                bfp162 p2 = __float22bfloat162_rn(make_float2(a[4], a[5]));
                bfp162 p3 = __float22bfloat162_rn(make_float2(a[6], a[7]));
                i32x4 o;
                o.x = *reinterpret_cast<int*>(&p0);
                o.y = *reinterpret_cast<int*>(&p1);
                o.z = *reinterpret_cast<int*>(&p2);
                o.w = *reinterpret_cast<int*>(&p3);
                *(i32x4*)&eab[(size_t)i * HID + c0] = o;
            } else {
                s16x8 av = *(const s16x8*)&eab[(size_t)i * HID + c0];  // CSR-linear
#pragma unroll
                for (int j = 0; j < 8; j++) a[j] = b2f(av[j]);
            }
            s16x8 hv = *(const s16x8*)&hz[(size_t)pr.y * HID + c0];
#pragma unroll
            for (int j = 0; j < 8; j++) {
                float hf = b2f(hv[j]);
                if (BN) hf = fmaxf(hf * sc[j] + sf[j], 0.f);
                acc[j] += fmaxf(a[j] + hf, 0.f);
            }
        };

        int i = beg + slot;
        for (; i + 4 < end; i += 8) {
            body(i);
            body(i + 4);
        }
        if (i < end) body(i);

#pragma unroll
        for (int j = 0; j < 8; j++) {
            acc[j] += __shfl_xor(acc[j], 16);
            acc[j] += __shfl_xor(acc[j], 32);
        }

        if (lane < 16) {
            s16x8 hv = *(const s16x8*)&hz[(size_t)nid * HID + c0];
            bfp162 pk[4];
#pragma unroll
            for (int j = 0; j < 4; j++) {
                float h0 = b2f(hv[2 * j]);
                float h1 = b2f(hv[2 * j + 1]);
                if (BN) {
                    h0 = fmaxf(h0 * sc[2 * j] + sf[2 * j], 0.f);
                    h1 = fmaxf(h1 * sc[2 * j + 1] + sf[2 * j + 1], 0.f);
                }
                pk[j] = __float22bfloat162_rn(make_float2(acc[2 * j] + h0,
                                                          acc[2 * j + 1] + h1));
            }
            i32x4 o;
            o.x = *reinterpret_cast<int*>(&pk[0]);
            o.y = *reinterpret_cast<int*>(&pk[1]);
            o.z = *reinterpret_cast<int*>(&pk[2]);
            o.w = *reinterpret_cast<int*>(&pk[3]);
            *(i32x4*)&z[(size_t)nid * HID + c0] = o;
        }
    }
}

// ---------------- fused MLP: z2 = relu(A@W1+b1)@W2+b2, + BN col sums -------
// REP: instrumentation repeats; stats atomic only on last rep.
template <int REP>
__global__ __launch_bounds__(256) void k_mlp(const bfp16* __restrict__ A,
                                             const bfp16* __restrict__ Wt1,
                                             const bfp16* __restrict__ Wt2,
                                             const float* __restrict__ b1,
                                             const float* __restrict__ b2,
                                             bfp16* __restrict__ z2,
                                             float* __restrict__ stats,
                                             int N) {
    __shared__ __align__(16) short sW1[128 * 128];
    __shared__ __align__(16) short sW2[128 * 128];
    __shared__ __align__(16) short sA[64 * 128];
    const int t = threadIdx.x;
    const int rowBase = blockIdx.x * 64;
    const short* W1g = (const short*)Wt1;
    const short* W2g = (const short*)Wt2;
    const short* Ag = (const short*)A;

    const int w = t >> 6, lane = t & 63;
    const int l15 = lane & 15, lhi = lane >> 4;
    const int arow = (w << 4) + l15;
    const int abase = arow * 128, asw = arow & 7;
    const int bsw = l15 & 7;

    for (int rep = 0; rep < REP; ++rep) {
        for (int g = t; g < 2048; g += 256) {
            int nrow = g >> 4, s = g & 15;
            int sw = nrow * 128 + ((s ^ (nrow & 7)) << 3);
            *(float4*)&sW1[sw] = *(const float4*)&W1g[g * 8];
            *(float4*)&sW2[sw] = *(const float4*)&W2g[g * 8];
        }
        for (int g = t; g < 1024; g += 256) {
            int r = g >> 4, s = g & 15;
            float4 v = make_float4(0.f, 0.f, 0.f, 0.f);
            if (rowBase + r < N)
                v = *(const float4*)&Ag[(size_t)(rowBase + r) * 128 + s * 8];
            *(float4*)&sA[r * 128 + ((s ^ (r & 7)) << 3)] = v;
        }
        __syncthreads();

        f32x4 acc[8];
#pragma unroll
        for (int c = 0; c < 8; c++) acc[c] = (f32x4){0.f, 0.f, 0.f, 0.f};
#pragma unroll
        for (int kk = 0; kk < 4; kk++) {
            int kslot = kk * 4 + lhi;
            s16x8 af = *(const s16x8*)&sA[abase + ((kslot ^ asw) << 3)];
#pragma unroll
            for (int c = 0; c < 8; c++) {
                s16x8 bfr = *(const s16x8*)&sW1[(c * 16 + l15) * 128 +
                                                ((kslot ^ bsw) << 3)];
                acc[c] = __builtin_amdgcn_mfma_f32_16x16x32_bf16(af, bfr, acc[c],
                                                                 0, 0, 0);
            }
        }
        __syncthreads();

        {
            const int rowb = (w << 4);
#pragma unroll
            for (int c = 0; c < 8; c++) {
                float bb = b1[c * 16 + l15];
                int col = c * 16 + l15;
#pragma unroll
                for (int r = 0; r < 4; r++) {
                    int row = rowb + lhi * 4 + r;
                    float v = fmaxf(acc[c][r] + bb, 0.f);
                    bfp16 bv = __float2bfloat16(v);
                    sA[row * 128 + ((((col >> 3)) ^ (row & 7)) << 3) + (col & 7)] =
                        *reinterpret_cast<short*>(&bv);
                }
            }
        }
        __syncthreads();

        f32x4 acc2[8];
#pragma unroll
        for (int c = 0; c < 8; c++) acc2[c] = (f32x4){0.f, 0.f, 0.f, 0.f};
#pragma unroll
        for (int kk = 0; kk < 4; kk++) {
            int kslot = kk * 4 + lhi;
            s16x8 af = *(const s16x8*)&sA[abase + ((kslot ^ asw) << 3)];
#pragma unroll
            for (int c = 0; c < 8; c++) {
                s16x8 bfr = *(const s16x8*)&sW2[(c * 16 + l15) * 128 +
                                                ((kslot ^ bsw) << 3)];
                acc2[c] = __builtin_amdgcn_mfma_f32_16x16x32_bf16(af, bfr, acc2[c],
                                                                  0, 0, 0);
            }
        }

        const int rb = rowBase + (w << 4) + lhi * 4;
        float scol[8], qcol[8];
#pragma unroll
        for (int c = 0; c < 8; c++) {
            float bb = b2[c * 16 + l15];
            float s = 0.f, q = 0.f;
#pragma unroll
            for (int r = 0; r < 4; r++) {
                int row = rb + r;
                float v = acc2[c][r] + bb;
                if (row < N) {
                    z2[(size_t)row * 128 + c * 16 + l15] = __float2bfloat16(v);
                    s += v;
                    q += v * v;
                }
            }
            scol[c] = s;
            qcol[c] = q;
        }
#pragma unroll
        for (int c = 0; c < 8; c++) {
            scol[c] += __shfl_xor(scol[c], 16);
            scol[c] += __shfl_xor(scol[c], 32);
            qcol[c] += __shfl_xor(qcol[c], 16);
            qcol[c] += __shfl_xor(qcol[c], 32);
        }
        __syncthreads();
        float* sStat = (float*)sA;
        if (lane < 16) {
#pragma unroll
            for (int c = 0; c < 8; c++) {
                sStat[w * 256 + c * 16 + lane] = scol[c];
                sStat[w * 256 + 128 + c * 16 + lane] = qcol[c];
            }
        }
        __syncthreads();
        if (rep == REP - 1 && t < 128) {
            float ss = sStat[t] + sStat[256 + t] + sStat[512 + t] + sStat[768 + t];
            float qq = sStat[128 + t] + sStat[384 + t] + sStat[640 + t] +
                       sStat[896 + t];
            atomicAdd(&stats[t], ss);
            atomicAdd(&stats[128 + t], qq);
        }
        __syncthreads();
    }
}

// ---------------- final: BN(z2) -> per-graph mean pool -> dot --------------
__global__ __launch_bounds__(256) void k_finalpool(const bfp16* __restrict__ z2,
                                                   const float* __restrict__ stats,
                                                   const float* __restrict__ gamma,
                                                   const float* __restrict__ beta,
                                                   const int* __restrict__ batch,
                                                   const float* __restrict__ mol,
                                                   const float* __restrict__ Wf,
                                                   const float* __restrict__ bfp,
                                                   float* __restrict__ out) {
    int gid = (blockIdx.x * blockDim.x + threadIdx.x) >> 6;
    int lane = threadIdx.x & 63;
    if (gid >= NG) return;
    const int f = lane * 2;

    const float invn = 1.f / NN;
    float m0 = stats[f] * invn;
    float v0 = stats[128 + f] * invn - m0 * m0;
    float sc0 = rsqrtf(v0 + BN_EPS) * gamma[f];
    float sf0 = beta[f] - m0 * sc0;
    float m1 = stats[f + 1] * invn;
    float v1 = stats[128 + f + 1] * invn - m1 * m1;
    float sc1 = rsqrtf(v1 + BN_EPS) * gamma[f + 1];
    float sf1 = beta[f + 1] - m1 * sc1;

    int lo = 0, hi = NN;
    while (lo < hi) { int m = (lo + hi) >> 1; if (batch[m] < gid) lo = m + 1; else hi = m; }
    int lb = lo;
    hi = NN;
    while (lo < hi) { int m = (lo + hi) >> 1; if (batch[m] <= gid) lo = m + 1; else hi = m; }
    int cnt = lo - lb;

    float sx = 0.f, sy = 0.f;
    for (int n = lb; n < lo; n++) {
        float2 v = __bfloat1622float2(*(const bfp162*)&z2[(size_t)n * HID + f]);
        sx += fmaxf(v.x * sc0 + sf0, 0.f);
        sy += fmaxf(v.y * sc1 + sf1, 0.f);
    }
    float inv = 1.f / fmaxf((float)cnt, 1.f);
    float acc = sx * inv * Wf[f] + sy * inv * Wf[f + 1];
    if (lane < DESCD) acc += mol[(size_t)gid * DESCD + lane] * Wf[HID + lane];
#pragma unroll
    for (int o = 32; o > 0; o >>= 1) acc += __shfl_down(acc, o);
    if (lane == 0) out[gid] = acc + bfp[0];
}

extern "C" void kernel_launch(void* const* d_in, const int* in_sizes, int n_in,
                              void* d_out, int out_size, void* d_ws, size_t ws_size,
                              hipStream_t stream) {
    const float* x     = (const float*)d_in[0];
    const int*   ei    = (const int*)d_in[1];
    const float* ea    = (const float*)d_in[2];
    const int*   batch = (const int*)d_in[3];
    const float* mol   = (const float*)d_in[4];
    const float* Wp    = (const float*)d_in[5];
    const float* bp    = (const float*)d_in[6];
    const float* W1    = (const float*)d_in[7];
    const float* b1    = (const float*)d_in[8];
    const float* W2    = (const float*)d_in[9];
    const float* b2    = (const float*)d_in[10];
    const float* gamma = (const float*)d_in[11];
    const float* beta  = (const float*)d_in[12];
    const float* Wf    = (const float*)d_in[13];
    const float* bf_   = (const float*)d_in[14];
    float* out = (float*)d_out;

    char* p = (char*)d_ws;
    size_t off = 0;
    auto alloc = [&](size_t bytes) {
        char* q = p + off;
        off = (off + bytes + 255) & ~(size_t)255;
        return q;
    };
    bfp16* h      = (bfp16*)alloc((size_t)NN * HID * 2);
    bfp16* z      = (bfp16*)alloc((size_t)NN * HID * 2);
    bfp16* z2     = (bfp16*)alloc((size_t)NN * HID * 2);
    bfp16* Wt     = (bfp16*)alloc((size_t)6 * HID * HID * 2);
    int2*  perm   = (int2*)alloc((size_t)NE * 8);
    int*   rowptr = (int*)alloc((NN + 16) * 4);
    int*   cursor = (int*)alloc(NN * 4);
    int*   partials = (int*)alloc(NB_SCAN * 4);
    int*   poffs    = (int*)alloc(NB_SCAN * 4);
    // contiguous zero-init region: deg | stats3
    size_t zoff = off;
    int*   deg    = (int*)alloc(NN * 4);
    float* stats3 = (float*)alloc(3 * 256 * 4);
    size_t zlen = off - zoff;
    bfp16* eab    = (bfp16*)alloc((size_t)NE * HID * 2);

    const int* src = ei;
    const int* dst = ei + NE;

    (void)hipMemsetAsync(p + zoff, 0, zlen, stream);
    k_hist<<<(NE + 255) / 256, 256, 0, stream>>>(dst, deg);
    k_part<<<NB_SCAN, 256, 0, stream>>>(deg, partials);
    k_scanpart<<<1, 256, 0, stream>>>(partials, poffs);
    k_scatter<<<NB_SCAN, 256, 0, stream>>>(deg, poffs, rowptr, cursor);
    k_fill<<<(NE + 255) / 256, 256, 0, stream>>>(src, dst, cursor, perm);
    {
        const int projBlocks = (NN * HID) / 256;
        const int wprepBlocks = (6 * HID * HID + 255) / 256;
        k_projwprep<<<projBlocks + wprepBlocks, 256, 0, stream>>>(
            x, Wp, bp, h, W1, W2, Wt, projBlocks);
    }

    const int aggrGrid = (NN * 64) / 256;
    const int mlpGrid = (NN + 63) / 64;
    for (int l = 0; l < NL; l++) {
        if (l == 0)
            k_aggr<1, false, 3><<<aggrGrid, 256, 0, stream>>>(
                h, ea, eab, perm, rowptr, nullptr, nullptr, nullptr, z);
        else
            k_aggr<2, true, 7><<<aggrGrid, 256, 0, stream>>>(
                z2, nullptr, eab, perm, rowptr, stats3 + (l - 1) * 256,
                gamma + (l - 1) * HID, beta + (l - 1) * HID, z);
        k_mlp<9><<<mlpGrid, 256, 0, stream>>>(
            z, Wt + (size_t)l * HID * HID, Wt + (size_t)(3 + l) * HID * HID,
            b1 + l * HID, b2 + l * HID, z2, stats3 + l * 256, NN);
    }

    k_finalpool<<<(NG * 64) / 256, 256, 0, stream>>>(
        z2, stats3 + 2 * 256, gamma + 2 * HID, beta + 2 * HID,
        batch, mol, Wf, bf_, out);
}

// Round 16
// 442.139 us; speedup vs baseline: 2.6088x; 2.6088x over previous
//
#include <hip/hip_runtime.h>
#include <hip/hip_bf16.h>

#define NN 50000
#define NE 600000
#define NG 1000
#define IND 16
#define HID 128
#define DESCD 17
#define NL 3
#define BN_EPS 1e-5f
#define NB_SCAN 196  // ceil(NN/256)

typedef short s16x8 __attribute__((ext_vector_type(8)));
typedef float f32x4 __attribute__((ext_vector_type(4)));
typedef int   i32x4 __attribute__((ext_vector_type(4)));
typedef __hip_bfloat16 bfp16;
typedef __hip_bfloat162 bfp162;

__device__ __forceinline__ float b2f(short s) {
    return __uint_as_float(((unsigned int)(unsigned short)s) << 16);
}

// ---------------- CSR build ----------------
__global__ __launch_bounds__(256) void k_hist(const int* __restrict__ dst,
                                              int* __restrict__ deg) {
    int e = blockIdx.x * blockDim.x + threadIdx.x;
    if (e >= NE) return;
    atomicAdd(&deg[dst[e]], 1);
}

__global__ __launch_bounds__(256) void k_part(const int* __restrict__ deg,
                                              int* __restrict__ partials) {
    __shared__ int sh[256];
    int i = blockIdx.x * 256 + threadIdx.x;
    sh[threadIdx.x] = (i < NN) ? deg[i] : 0;
    __syncthreads();
    for (int o = 128; o > 0; o >>= 1) {
        if (threadIdx.x < o) sh[threadIdx.x] += sh[threadIdx.x + o];
        __syncthreads();
    }
    if (threadIdx.x == 0) partials[blockIdx.x] = sh[0];
}

__global__ __launch_bounds__(256) void k_scanpart(const int* __restrict__ partials,
                                                  int* __restrict__ poffs) {
    __shared__ int sh[256];
    int t = threadIdx.x;
    int v = (t < NB_SCAN) ? partials[t] : 0;
    sh[t] = v;
    __syncthreads();
    for (int o = 1; o < 256; o <<= 1) {
        int tmp = (t >= o) ? sh[t - o] : 0;
        __syncthreads();
        sh[t] += tmp;
        __syncthreads();
    }
    if (t < NB_SCAN) poffs[t] = sh[t] - v;
}

__global__ __launch_bounds__(256) void k_scatter(const int* __restrict__ deg,
                                                 const int* __restrict__ poffs,
                                                 int* __restrict__ rowptr,
                                                 int* __restrict__ cursor) {
    __shared__ int sh[256];
    int b = blockIdx.x, t = threadIdx.x;
    int i = b * 256 + t;
    int v = (i < NN) ? deg[i] : 0;
    sh[t] = v;
    __syncthreads();
    for (int o = 1; o < 256; o <<= 1) {
        int tmp = (t >= o) ? sh[t - o] : 0;
        __syncthreads();
        sh[t] += tmp;
        __syncthreads();
    }
    int excl = sh[t] - v + poffs[b];
    if (i < NN) {
        rowptr[i] = excl;
        cursor[i] = excl;
        if (i == NN - 1) rowptr[NN] = excl + v;
    }
}

// ---------------- fused: CSR fill + proj + wprep (one dispatch) ------------
__global__ __launch_bounds__(256) void k_fillproj(const int* __restrict__ src,
                                                  const int* __restrict__ dst,
                                                  int* __restrict__ cursor,
                                                  int2* __restrict__ perm,
                                                  const float* __restrict__ x,
                                                  const float* __restrict__ Wp,
                                                  const float* __restrict__ bp,
                                                  bfp16* __restrict__ h,
                                                  const float* __restrict__ W1,
                                                  const float* __restrict__ W2,
                                                  bfp16* __restrict__ Wt,
                                                  int fillBlocks, int projBlocks) {
    if (blockIdx.x < (unsigned)fillBlocks) {
        int e = blockIdx.x * blockDim.x + threadIdx.x;
        if (e >= NE) return;
        int pos = atomicAdd(&cursor[dst[e]], 1);
        perm[pos] = make_int2(e, src[e]);
    } else if (blockIdx.x < (unsigned)(fillBlocks + projBlocks)) {
        int idx = (blockIdx.x - fillBlocks) * blockDim.x + threadIdx.x;
        if (idx >= NN * HID) return;
        int row = idx >> 7, col = idx & 127;
        const float* xr = x + (size_t)row * IND;
        float acc = bp[col];
#pragma unroll
        for (int k = 0; k < IND; k++) acc += xr[k] * Wp[k * HID + col];
        h[idx] = __float2bfloat16(acc);
    } else {
        int id = (blockIdx.x - fillBlocks - projBlocks) * blockDim.x + threadIdx.x;
        if (id >= 6 * HID * HID) return;
        int m = id >> 14;
        int rem = id & 16383;
        int n = rem >> 7, k = rem & 127;
        const float* Wsrc = (m < 3) ? (W1 + (size_t)m * HID * HID)
                                    : (W2 + (size_t)(m - 3) * HID * HID);
        Wt[id] = __float2bfloat16(Wsrc[k * HID + n]);
    }
}

// ---------------- gather aggregation, 4 edges/wave, 16B/lane ---------------
template <int MODE, bool BN>
__global__ __launch_bounds__(256) void k_aggr(const bfp16* __restrict__ hz,
                                              const float* __restrict__ ea,
                                              bfp16* __restrict__ eab,
                                              const int2* __restrict__ perm,
                                              const int* __restrict__ rowptr,
                                              const float* __restrict__ stats,
                                              const float* __restrict__ gamma,
                                              const float* __restrict__ beta,
                                              bfp16* __restrict__ z) {
    int nid = (blockIdx.x * blockDim.x + threadIdx.x) >> 6;
    int lane = threadIdx.x & 63;
    if (nid >= NN) return;
    const int slot = lane >> 4;
    const int c0 = (lane & 15) << 3;

    float sc[8], sf[8];
    if (BN) {
        const float invn = 1.f / NN;
#pragma unroll
        for (int j = 0; j < 8; j++) {
            int c = c0 + j;
            float m = stats[c] * invn;
            float v = stats[128 + c] * invn - m * m;
            sc[j] = rsqrtf(v + BN_EPS) * gamma[c];
            sf[j] = beta[c] - m * sc[j];
        }
    }

    float acc[8];
#pragma unroll
    for (int j = 0; j < 8; j++) acc[j] = 0.f;

    auto body = [&](int i) {
        int2 pr = perm[i];
        float a[8];
        if (MODE == 1) {
            f32x4 a0 = __builtin_nontemporal_load(
                (const f32x4*)&ea[(size_t)pr.x * HID + c0]);
            f32x4 a1 = __builtin_nontemporal_load(
                (const f32x4*)&ea[(size_t)pr.x * HID + c0 + 4]);
            a[0] = a0.x; a[1] = a0.y; a[2] = a0.z; a[3] = a0.w;
            a[4] = a1.x; a[5] = a1.y; a[6] = a1.z; a[7] = a1.w;
            bfp162 p0 = __float22bfloat162_rn(make_float2(a[0], a[1]));
            bfp162 p1 = __float22bfloat162_rn(make_float2(a[2], a[3]));
            bfp162 p2 = __float22bfloat162_rn(make_float2(a[4], a[5]));
            bfp162 p3 = __float22bfloat162_rn(make_float2(a[6], a[7]));
            i32x4 o;
            o.x = *reinterpret_cast<int*>(&p0);
            o.y = *reinterpret_cast<int*>(&p1);
            o.z = *reinterpret_cast<int*>(&p2);
            o.w = *reinterpret_cast<int*>(&p3);
            *(i32x4*)&eab[(size_t)i * HID + c0] = o;
        } else {
            s16x8 av = *(const s16x8*)&eab[(size_t)i * HID + c0];  // CSR-linear
#pragma unroll
            for (int j = 0; j < 8; j++) a[j] = b2f(av[j]);
        }
        s16x8 hv = *(const s16x8*)&hz[(size_t)pr.y * HID + c0];
#pragma unroll
        for (int j = 0; j < 8; j++) {
            float hf = b2f(hv[j]);
            if (BN) hf = fmaxf(hf * sc[j] + sf[j], 0.f);
            acc[j] += fmaxf(a[j] + hf, 0.f);
        }
    };

    int beg = rowptr[nid], end = rowptr[nid + 1];
    int i = beg + slot;
    for (; i + 4 < end; i += 8) {
        body(i);
        body(i + 4);
    }
    if (i < end) body(i);

#pragma unroll
    for (int j = 0; j < 8; j++) {
        acc[j] += __shfl_xor(acc[j], 16);
        acc[j] += __shfl_xor(acc[j], 32);
    }

    if (lane < 16) {
        s16x8 hv = *(const s16x8*)&hz[(size_t)nid * HID + c0];
        bfp162 pk[4];
#pragma unroll
        for (int j = 0; j < 4; j++) {
            float h0 = b2f(hv[2 * j]);
            float h1 = b2f(hv[2 * j + 1]);
            if (BN) {
                h0 = fmaxf(h0 * sc[2 * j] + sf[2 * j], 0.f);
                h1 = fmaxf(h1 * sc[2 * j + 1] + sf[2 * j + 1], 0.f);
            }
            pk[j] = __float22bfloat162_rn(make_float2(acc[2 * j] + h0,
                                                      acc[2 * j + 1] + h1));
        }
        i32x4 o;
        o.x = *reinterpret_cast<int*>(&pk[0]);
        o.y = *reinterpret_cast<int*>(&pk[1]);
        o.z = *reinterpret_cast<int*>(&pk[2]);
        o.w = *reinterpret_cast<int*>(&pk[3]);
        *(i32x4*)&z[(size_t)nid * HID + c0] = o;
    }
}

// ---------------- fused MLP: z2 = relu(A@W1+b1)@W2+b2, + BN col sums -------
// LDS = 48 KB (sW 32 KB staged W1 then W2, sA 16 KB) -> 3 blocks/CU,
// 768 concurrent slots for 782 tiles => single scheduling round (no tail).
__global__ __launch_bounds__(256) void k_mlp(const bfp16* __restrict__ A,
                                             const bfp16* __restrict__ Wt1,
                                             const bfp16* __restrict__ Wt2,
                                             const float* __restrict__ b1,
                                             const float* __restrict__ b2,
                                             bfp16* __restrict__ z2,
                                             float* __restrict__ stats,
                                             int N) {
    __shared__ __align__(16) short sW[128 * 128];   // 32 KB: W1, then W2
    __shared__ __align__(16) short sA[64 * 128];    // 16 KB: A, then y1, then stats
    const int t = threadIdx.x;
    const int rowBase = blockIdx.x * 64;

    const short* W1g = (const short*)Wt1;
    const short* W2g = (const short*)Wt2;
    for (int g = t; g < 2048; g += 256) {
        int nrow = g >> 4, s = g & 15;
        int sw = nrow * 128 + ((s ^ (nrow & 7)) << 3);
        *(float4*)&sW[sw] = *(const float4*)&W1g[g * 8];
    }
    const short* Ag = (const short*)A;
    for (int g = t; g < 1024; g += 256) {
        int r = g >> 4, s = g & 15;
        float4 v = make_float4(0.f, 0.f, 0.f, 0.f);
        if (rowBase + r < N) v = *(const float4*)&Ag[(size_t)(rowBase + r) * 128 + s * 8];
        *(float4*)&sA[r * 128 + ((s ^ (r & 7)) << 3)] = v;
    }
    __syncthreads();

    const int w = t >> 6, lane = t & 63;
    const int l15 = lane & 15, lhi = lane >> 4;
    const int arow = (w << 4) + l15;
    const int abase = arow * 128, asw = arow & 7;
    const int bsw = l15 & 7;

    // phase 1: y1 = A @ W1
    f32x4 acc[8];
#pragma unroll
    for (int c = 0; c < 8; c++) acc[c] = (f32x4){0.f, 0.f, 0.f, 0.f};
#pragma unroll
    for (int kk = 0; kk < 4; kk++) {
        int kslot = kk * 4 + lhi;
        s16x8 af = *(const s16x8*)&sA[abase + ((kslot ^ asw) << 3)];
#pragma unroll
        for (int c = 0; c < 8; c++) {
            s16x8 bfr = *(const s16x8*)&sW[(c * 16 + l15) * 128 + ((kslot ^ bsw) << 3)];
            acc[c] = __builtin_amdgcn_mfma_f32_16x16x32_bf16(af, bfr, acc[c], 0, 0, 0);
        }
    }
    __syncthreads();  // phase-1 LDS reads done; sA -> y1, sW -> W2

    {
        const int rowb = (w << 4);
#pragma unroll
        for (int c = 0; c < 8; c++) {
            float bb = b1[c * 16 + l15];
            int col = c * 16 + l15;
#pragma unroll
            for (int r = 0; r < 4; r++) {
                int row = rowb + lhi * 4 + r;
                float v = fmaxf(acc[c][r] + bb, 0.f);
                bfp16 bv = __float2bfloat16(v);
                sA[row * 128 + ((((col >> 3)) ^ (row & 7)) << 3) + (col & 7)] =
                    *reinterpret_cast<short*>(&bv);
            }
        }
    }
    for (int g = t; g < 2048; g += 256) {
        int nrow = g >> 4, s = g & 15;
        int sw = nrow * 128 + ((s ^ (nrow & 7)) << 3);
        *(float4*)&sW[sw] = *(const float4*)&W2g[g * 8];
    }
    __syncthreads();

    // phase 2: z2 = y1 @ W2
    f32x4 acc2[8];
#pragma unroll
    for (int c = 0; c < 8; c++) acc2[c] = (f32x4){0.f, 0.f, 0.f, 0.f};
#pragma unroll
    for (int kk = 0; kk < 4; kk++) {
        int kslot = kk * 4 + lhi;
        s16x8 af = *(const s16x8*)&sA[abase + ((kslot ^ asw) << 3)];
#pragma unroll
        for (int c = 0; c < 8; c++) {
            s16x8 bfr = *(const s16x8*)&sW[(c * 16 + l15) * 128 + ((kslot ^ bsw) << 3)];
            acc2[c] = __builtin_amdgcn_mfma_f32_16x16x32_bf16(af, bfr, acc2[c], 0, 0, 0);
        }
    }

    const int rb = rowBase + (w << 4) + lhi * 4;
    float scol[8], qcol[8];
#pragma unroll
    for (int c = 0; c < 8; c++) {
        float bb = b2[c * 16 + l15];
        float s = 0.f, q = 0.f;
#pragma unroll
        for (int r = 0; r < 4; r++) {
            int row = rb + r;
            float v = acc2[c][r] + bb;
            if (row < N) {
                z2[(size_t)row * 128 + c * 16 + l15] = __float2bfloat16(v);
                s += v;
                q += v * v;
            }
        }
        scol[c] = s;
        qcol[c] = q;
    }
#pragma unroll
    for (int c = 0; c < 8; c++) {
        scol[c] += __shfl_xor(scol[c], 16);
        scol[c] += __shfl_xor(scol[c], 32);
        qcol[c] += __shfl_xor(qcol[c], 16);
        qcol[c] += __shfl_xor(qcol[c], 32);
    }
    __syncthreads();  // phase-2 sA reads done; reuse as stats buffer
    float* sStat = (float*)sA;
    if (lane < 16) {
#pragma unroll
        for (int c = 0; c < 8; c++) {
            sStat[w * 256 + c * 16 + lane] = scol[c];
            sStat[w * 256 + 128 + c * 16 + lane] = qcol[c];
        }
    }
    __syncthreads();
    if (t < 128) {
        float ss = sStat[t] + sStat[256 + t] + sStat[512 + t] + sStat[768 + t];
        float qq = sStat[128 + t] + sStat[384 + t] + sStat[640 + t] + sStat[896 + t];
        atomicAdd(&stats[t], ss);
        atomicAdd(&stats[128 + t], qq);
    }
}

// ---------------- final: BN(z2) -> per-graph mean pool -> dot --------------
__global__ __launch_bounds__(256) void k_finalpool(const bfp16* __restrict__ z2,
                                                   const float* __restrict__ stats,
                                                   const float* __restrict__ gamma,
                                                   const float* __restrict__ beta,
                                                   const int* __restrict__ batch,
                                                   const float* __restrict__ mol,
                                                   const float* __restrict__ Wf,
                                                   const float* __restrict__ bfp,
                                                   float* __restrict__ out) {
    int gid = (blockIdx.x * blockDim.x + threadIdx.x) >> 6;
    int lane = threadIdx.x & 63;
    if (gid >= NG) return;
    const int f = lane * 2;

    const float invn = 1.f / NN;
    float m0 = stats[f] * invn;
    float v0 = stats[128 + f] * invn - m0 * m0;
    float sc0 = rsqrtf(v0 + BN_EPS) * gamma[f];
    float sf0 = beta[f] - m0 * sc0;
    float m1 = stats[f + 1] * invn;
    float v1 = stats[128 + f + 1] * invn - m1 * m1;
    float sc1 = rsqrtf(v1 + BN_EPS) * gamma[f + 1];
    float sf1 = beta[f + 1] - m1 * sc1;

    int lo = 0, hi = NN;
    while (lo < hi) { int m = (lo + hi) >> 1; if (batch[m] < gid) lo = m + 1; else hi = m; }
    int lb = lo;
    hi = NN;
    while (lo < hi) { int m = (lo + hi) >> 1; if (batch[m] <= gid) lo = m + 1; else hi = m; }
    int cnt = lo - lb;

    float sx = 0.f, sy = 0.f;
    for (int n = lb; n < lo; n++) {
        float2 v = __bfloat1622float2(*(const bfp162*)&z2[(size_t)n * HID + f]);
        sx += fmaxf(v.x * sc0 + sf0, 0.f);
        sy += fmaxf(v.y * sc1 + sf1, 0.f);
    }
    float inv = 1.f / fmaxf((float)cnt, 1.f);
    float acc = sx * inv * Wf[f] + sy * inv * Wf[f + 1];
    if (lane < DESCD) acc += mol[(size_t)gid * DESCD + lane] * Wf[HID + lane];
#pragma unroll
    for (int o = 32; o > 0; o >>= 1) acc += __shfl_down(acc, o);
    if (lane == 0) out[gid] = acc + bfp[0];
}

extern "C" void kernel_launch(void* const* d_in, const int* in_sizes, int n_in,
                              void* d_out, int out_size, void* d_ws, size_t ws_size,
                              hipStream_t stream) {
    const float* x     = (const float*)d_in[0];
    const int*   ei    = (const int*)d_in[1];
    const float* ea    = (const float*)d_in[2];
    const int*   batch = (const int*)d_in[3];
    const float* mol   = (const float*)d_in[4];
    const float* Wp    = (const float*)d_in[5];
    const float* bp    = (const float*)d_in[6];
    const float* W1    = (const float*)d_in[7];
    const float* b1    = (const float*)d_in[8];
    const float* W2    = (const float*)d_in[9];
    const float* b2    = (const float*)d_in[10];
    const float* gamma = (const float*)d_in[11];
    const float* beta  = (const float*)d_in[12];
    const float* Wf    = (const float*)d_in[13];
    const float* bf_   = (const float*)d_in[14];
    float* out = (float*)d_out;

    char* p = (char*)d_ws;
    size_t off = 0;
    auto alloc = [&](size_t bytes) {
        char* q = p + off;
        off = (off + bytes + 255) & ~(size_t)255;
        return q;
    };
    bfp16* h      = (bfp16*)alloc((size_t)NN * HID * 2);
    bfp16* z      = (bfp16*)alloc((size_t)NN * HID * 2);
    bfp16* z2     = (bfp16*)alloc((size_t)NN * HID * 2);
    bfp16* Wt     = (bfp16*)alloc((size_t)6 * HID * HID * 2);
    int2*  perm   = (int2*)alloc((size_t)NE * 8);
    int*   rowptr = (int*)alloc((NN + 16) * 4);
    int*   cursor = (int*)alloc(NN * 4);
    int*   partials = (int*)alloc(NB_SCAN * 4);
    int*   poffs    = (int*)alloc(NB_SCAN * 4);
    // contiguous zero-init region: deg | stats3
    size_t zoff = off;
    int*   deg    = (int*)alloc(NN * 4);
    float* stats3 = (float*)alloc(3 * 256 * 4);
    size_t zlen = off - zoff;
    bfp16* eab    = (bfp16*)alloc((size_t)NE * HID * 2);

    const int* src = ei;
    const int* dst = ei + NE;

    (void)hipMemsetAsync(p + zoff, 0, zlen, stream);
    k_hist<<<(NE + 255) / 256, 256, 0, stream>>>(dst, deg);
    k_part<<<NB_SCAN, 256, 0, stream>>>(deg, partials);
    k_scanpart<<<1, 256, 0, stream>>>(partials, poffs);
    k_scatter<<<NB_SCAN, 256, 0, stream>>>(deg, poffs, rowptr, cursor);
    {
        const int fillBlocks = (NE + 255) / 256;
        const int projBlocks = (NN * HID) / 256;
        const int wprepBlocks = (6 * HID * HID + 255) / 256;
        k_fillproj<<<fillBlocks + projBlocks + wprepBlocks, 256, 0, stream>>>(
            src, dst, cursor, perm, x, Wp, bp, h, W1, W2, Wt,
            fillBlocks, projBlocks);
    }

    const int aggrGrid = (NN * 64) / 256;
    const int mlpGrid = (NN + 63) / 64;
    for (int l = 0; l < NL; l++) {
        if (l == 0)
            k_aggr<1, false><<<aggrGrid, 256, 0, stream>>>(
                h, ea, eab, perm, rowptr, nullptr, nullptr, nullptr, z);
        else
            k_aggr<2, true><<<aggrGrid, 256, 0, stream>>>(
                z2, nullptr, eab, perm, rowptr, stats3 + (l - 1) * 256,
                gamma + (l - 1) * HID, beta + (l - 1) * HID, z);
        k_mlp<<<mlpGrid, 256, 0, stream>>>(
            z, Wt + (size_t)l * HID * HID, Wt + (size_t)(3 + l) * HID * HID,
            b1 + l * HID, b2 + l * HID, z2, stats3 + l * 256, NN);
    }

    k_finalpool<<<(NG * 64) / 256, 256, 0, stream>>>(
        z2, stats3 + 2 * 256, gamma + 2 * HID, beta + 2 * HID,
        batch, mol, Wf, bf_, out);
}

// Round 17
// 429.396 us; speedup vs baseline: 2.6862x; 1.0297x over previous
//
#include <hip/hip_runtime.h>
#include <hip/hip_bf16.h>

#define NN 50000
#define NE 600000
#define NG 1000
#define IND 16
#define HID 128
#define DESCD 17
#define NL 3
#define BN_EPS 1e-5f
#define NB_SCAN 196  // ceil(NN/256)

typedef short s16x8 __attribute__((ext_vector_type(8)));
typedef float f32x4 __attribute__((ext_vector_type(4)));
typedef int   i32x4 __attribute__((ext_vector_type(4)));
typedef __hip_bfloat16 bfp16;
typedef __hip_bfloat162 bfp162;

__device__ __forceinline__ float b2f(short s) {
    return __uint_as_float(((unsigned int)(unsigned short)s) << 16);
}

// bijective XCD swizzle (m204): round-robin bid -> per-XCD contiguous chunks
__device__ __forceinline__ int xcd_swz(int bid, int nwg) {
    int q = nwg >> 3, r = nwg & 7;
    int xcd = bid & 7, idx = bid >> 3;
    return (xcd < r ? xcd * (q + 1) : r * (q + 1) + (xcd - r) * q) + idx;
}

// ---------------- CSR build ----------------
__global__ __launch_bounds__(256) void k_hist(const int* __restrict__ dst,
                                              int* __restrict__ deg) {
    int e = blockIdx.x * blockDim.x + threadIdx.x;
    if (e >= NE) return;
    atomicAdd(&deg[dst[e]], 1);
}

__global__ __launch_bounds__(256) void k_part(const int* __restrict__ deg,
                                              int* __restrict__ partials) {
    __shared__ int sh[256];
    int i = blockIdx.x * 256 + threadIdx.x;
    sh[threadIdx.x] = (i < NN) ? deg[i] : 0;
    __syncthreads();
    for (int o = 128; o > 0; o >>= 1) {
        if (threadIdx.x < o) sh[threadIdx.x] += sh[threadIdx.x + o];
        __syncthreads();
    }
    if (threadIdx.x == 0) partials[blockIdx.x] = sh[0];
}

__global__ __launch_bounds__(256) void k_scanpart(const int* __restrict__ partials,
                                                  int* __restrict__ poffs) {
    __shared__ int sh[256];
    int t = threadIdx.x;
    int v = (t < NB_SCAN) ? partials[t] : 0;
    sh[t] = v;
    __syncthreads();
    for (int o = 1; o < 256; o <<= 1) {
        int tmp = (t >= o) ? sh[t - o] : 0;
        __syncthreads();
        sh[t] += tmp;
        __syncthreads();
    }
    if (t < NB_SCAN) poffs[t] = sh[t] - v;
}

__global__ __launch_bounds__(256) void k_scatter(const int* __restrict__ deg,
                                                 const int* __restrict__ poffs,
                                                 int* __restrict__ rowptr,
                                                 int* __restrict__ cursor) {
    __shared__ int sh[256];
    int b = blockIdx.x, t = threadIdx.x;
    int i = b * 256 + t;
    int v = (i < NN) ? deg[i] : 0;
    sh[t] = v;
    __syncthreads();
    for (int o = 1; o < 256; o <<= 1) {
        int tmp = (t >= o) ? sh[t - o] : 0;
        __syncthreads();
        sh[t] += tmp;
        __syncthreads();
    }
    int excl = sh[t] - v + poffs[b];
    if (i < NN) {
        rowptr[i] = excl;
        cursor[i] = excl;
        if (i == NN - 1) rowptr[NN] = excl + v;
    }
}

// ---------------- fused: CSR fill + proj + wprep (one dispatch) ------------
__global__ __launch_bounds__(256) void k_fillproj(const int* __restrict__ src,
                                                  const int* __restrict__ dst,
                                                  int* __restrict__ cursor,
                                                  int2* __restrict__ perm,
                                                  const float* __restrict__ x,
                                                  const float* __restrict__ Wp,
                                                  const float* __restrict__ bp,
                                                  bfp16* __restrict__ h,
                                                  const float* __restrict__ W1,
                                                  const float* __restrict__ W2,
                                                  bfp16* __restrict__ Wt,
                                                  int fillBlocks, int projBlocks) {
    if (blockIdx.x < (unsigned)fillBlocks) {
        int e = blockIdx.x * blockDim.x + threadIdx.x;
        if (e >= NE) return;
        int pos = atomicAdd(&cursor[dst[e]], 1);
        perm[pos] = make_int2(e, src[e]);
    } else if (blockIdx.x < (unsigned)(fillBlocks + projBlocks)) {
        int idx = (blockIdx.x - fillBlocks) * blockDim.x + threadIdx.x;
        if (idx >= NN * HID) return;
        int row = idx >> 7, col = idx & 127;
        const float* xr = x + (size_t)row * IND;
        float acc = bp[col];
#pragma unroll
        for (int k = 0; k < IND; k++) acc += xr[k] * Wp[k * HID + col];
        h[idx] = __float2bfloat16(acc);
    } else {
        int id = (blockIdx.x - fillBlocks - projBlocks) * blockDim.x + threadIdx.x;
        if (id >= 6 * HID * HID) return;
        int m = id >> 14;
        int rem = id & 16383;
        int n = rem >> 7, k = rem & 127;
        const float* Wsrc = (m < 3) ? (W1 + (size_t)m * HID * HID)
                                    : (W2 + (size_t)(m - 3) * HID * HID);
        Wt[id] = __float2bfloat16(Wsrc[k * HID + n]);
    }
}

// ---------------- gather aggregation, 4 edges/wave, 16B/lane ---------------
// XCD-swizzled blockIdx for L2 locality on h-gather + eab stream.
template <int MODE, bool BN>
__global__ __launch_bounds__(256) void k_aggr(const bfp16* __restrict__ hz,
                                              const float* __restrict__ ea,
                                              bfp16* __restrict__ eab,
                                              const int2* __restrict__ perm,
                                              const int* __restrict__ rowptr,
                                              const float* __restrict__ stats,
                                              const float* __restrict__ gamma,
                                              const float* __restrict__ beta,
                                              bfp16* __restrict__ z) {
    int sb = xcd_swz(blockIdx.x, gridDim.x);
    int nid = (sb * 256 + threadIdx.x) >> 6;
    int lane = threadIdx.x & 63;
    if (nid >= NN) return;
    const int slot = lane >> 4;
    const int c0 = (lane & 15) << 3;

    float sc[8], sf[8];
    if (BN) {
        const float invn = 1.f / NN;
#pragma unroll
        for (int j = 0; j < 8; j++) {
            int c = c0 + j;
            float m = stats[c] * invn;
            float v = stats[128 + c] * invn - m * m;
            sc[j] = rsqrtf(v + BN_EPS) * gamma[c];
            sf[j] = beta[c] - m * sc[j];
        }
    }

    float acc[8];
#pragma unroll
    for (int j = 0; j < 8; j++) acc[j] = 0.f;

    auto body = [&](int i) {
        int2 pr = perm[i];
        float a[8];
        if (MODE == 1) {
            f32x4 a0 = __builtin_nontemporal_load(
                (const f32x4*)&ea[(size_t)pr.x * HID + c0]);
            f32x4 a1 = __builtin_nontemporal_load(
                (const f32x4*)&ea[(size_t)pr.x * HID + c0 + 4]);
            a[0] = a0.x; a[1] = a0.y; a[2] = a0.z; a[3] = a0.w;
            a[4] = a1.x; a[5] = a1.y; a[6] = a1.z; a[7] = a1.w;
            bfp162 p0 = __float22bfloat162_rn(make_float2(a[0], a[1]));
            bfp162 p1 = __float22bfloat162_rn(make_float2(a[2], a[3]));
            bfp162 p2 = __float22bfloat162_rn(make_float2(a[4], a[5]));
            bfp162 p3 = __float22bfloat162_rn(make_float2(a[6], a[7]));
            i32x4 o;
            o.x = *reinterpret_cast<int*>(&p0);
            o.y = *reinterpret_cast<int*>(&p1);
            o.z = *reinterpret_cast<int*>(&p2);
            o.w = *reinterpret_cast<int*>(&p3);
            *(i32x4*)&eab[(size_t)i * HID + c0] = o;
        } else {
            s16x8 av = *(const s16x8*)&eab[(size_t)i * HID + c0];  // CSR-linear
#pragma unroll
            for (int j = 0; j < 8; j++) a[j] = b2f(av[j]);
        }
        s16x8 hv = *(const s16x8*)&hz[(size_t)pr.y * HID + c0];
#pragma unroll
        for (int j = 0; j < 8; j++) {
            float hf = b2f(hv[j]);
            if (BN) hf = fmaxf(hf * sc[j] + sf[j], 0.f);
            acc[j] += fmaxf(a[j] + hf, 0.f);
        }
    };

    int beg = rowptr[nid], end = rowptr[nid + 1];
    int i = beg + slot;
    for (; i + 4 < end; i += 8) {
        body(i);
        body(i + 4);
    }
    if (i < end) body(i);

#pragma unroll
    for (int j = 0; j < 8; j++) {
        acc[j] += __shfl_xor(acc[j], 16);
        acc[j] += __shfl_xor(acc[j], 32);
    }

    if (lane < 16) {
        s16x8 hv = *(const s16x8*)&hz[(size_t)nid * HID + c0];
        bfp162 pk[4];
#pragma unroll
        for (int j = 0; j < 4; j++) {
            float h0 = b2f(hv[2 * j]);
            float h1 = b2f(hv[2 * j + 1]);
            if (BN) {
                h0 = fmaxf(h0 * sc[2 * j] + sf[2 * j], 0.f);
                h1 = fmaxf(h1 * sc[2 * j + 1] + sf[2 * j + 1], 0.f);
            }
            pk[j] = __float22bfloat162_rn(make_float2(acc[2 * j] + h0,
                                                      acc[2 * j + 1] + h1));
        }
        i32x4 o;
        o.x = *reinterpret_cast<int*>(&pk[0]);
        o.y = *reinterpret_cast<int*>(&pk[1]);
        o.z = *reinterpret_cast<int*>(&pk[2]);
        o.w = *reinterpret_cast<int*>(&pk[3]);
        *(i32x4*)&z[(size_t)nid * HID + c0] = o;
    }
}

// ---------------- fused MLP: z2 = relu(A@W1+b1)@W2+b2, + BN col sums -------
// (r14 known-best form: 80 KB LDS, weights staged once)
__global__ __launch_bounds__(256) void k_mlp(const bfp16* __restrict__ A,
                                             const bfp16* __restrict__ Wt1,
                                             const bfp16* __restrict__ Wt2,
                                             const float* __restrict__ b1,
                                             const float* __restrict__ b2,
                                             bfp16* __restrict__ z2,
                                             float* __restrict__ stats,
                                             int N) {
    __shared__ __align__(16) short sW1[128 * 128];
    __shared__ __align__(16) short sW2[128 * 128];
    __shared__ __align__(16) short sA[64 * 128];
    const int t = threadIdx.x;
    const int rowBase = blockIdx.x * 64;

    const short* W1g = (const short*)Wt1;
    const short* W2g = (const short*)Wt2;
    for (int g = t; g < 2048; g += 256) {
        int nrow = g >> 4, s = g & 15;
        int sw = nrow * 128 + ((s ^ (nrow & 7)) << 3);
        *(float4*)&sW1[sw] = *(const float4*)&W1g[g * 8];
        *(float4*)&sW2[sw] = *(const float4*)&W2g[g * 8];
    }
    const short* Ag = (const short*)A;
    for (int g = t; g < 1024; g += 256) {
        int r = g >> 4, s = g & 15;
        float4 v = make_float4(0.f, 0.f, 0.f, 0.f);
        if (rowBase + r < N) v = *(const float4*)&Ag[(size_t)(rowBase + r) * 128 + s * 8];
        *(float4*)&sA[r * 128 + ((s ^ (r & 7)) << 3)] = v;
    }
    __syncthreads();

    const int w = t >> 6, lane = t & 63;
    const int l15 = lane & 15, lhi = lane >> 4;
    const int arow = (w << 4) + l15;
    const int abase = arow * 128, asw = arow & 7;
    const int bsw = l15 & 7;

    f32x4 acc[8];
#pragma unroll
    for (int c = 0; c < 8; c++) acc[c] = (f32x4){0.f, 0.f, 0.f, 0.f};
#pragma unroll
    for (int kk = 0; kk < 4; kk++) {
        int kslot = kk * 4 + lhi;
        s16x8 af = *(const s16x8*)&sA[abase + ((kslot ^ asw) << 3)];
#pragma unroll
        for (int c = 0; c < 8; c++) {
            s16x8 bfr = *(const s16x8*)&sW1[(c * 16 + l15) * 128 + ((kslot ^ bsw) << 3)];
            acc[c] = __builtin_amdgcn_mfma_f32_16x16x32_bf16(af, bfr, acc[c], 0, 0, 0);
        }
    }
    __syncthreads();

    {
        const int rowb = (w << 4);
#pragma unroll
        for (int c = 0; c < 8; c++) {
            float bb = b1[c * 16 + l15];
            int col = c * 16 + l15;
#pragma unroll
            for (int r = 0; r < 4; r++) {
                int row = rowb + lhi * 4 + r;
                float v = fmaxf(acc[c][r] + bb, 0.f);
                bfp16 bv = __float2bfloat16(v);
                sA[row * 128 + ((((col >> 3)) ^ (row & 7)) << 3) + (col & 7)] =
                    *reinterpret_cast<short*>(&bv);
            }
        }
    }
    __syncthreads();

    f32x4 acc2[8];
#pragma unroll
    for (int c = 0; c < 8; c++) acc2[c] = (f32x4){0.f, 0.f, 0.f, 0.f};
#pragma unroll
    for (int kk = 0; kk < 4; kk++) {
        int kslot = kk * 4 + lhi;
        s16x8 af = *(const s16x8*)&sA[abase + ((kslot ^ asw) << 3)];
#pragma unroll
        for (int c = 0; c < 8; c++) {
            s16x8 bfr = *(const s16x8*)&sW2[(c * 16 + l15) * 128 + ((kslot ^ bsw) << 3)];
            acc2[c] = __builtin_amdgcn_mfma_f32_16x16x32_bf16(af, bfr, acc2[c], 0, 0, 0);
        }
    }

    const int rb = rowBase + (w << 4) + lhi * 4;
    float scol[8], qcol[8];
#pragma unroll
    for (int c = 0; c < 8; c++) {
        float bb = b2[c * 16 + l15];
        float s = 0.f, q = 0.f;
#pragma unroll
        for (int r = 0; r < 4; r++) {
            int row = rb + r;
            float v = acc2[c][r] + bb;
            if (row < N) {
                z2[(size_t)row * 128 + c * 16 + l15] = __float2bfloat16(v);
                s += v;
                q += v * v;
            }
        }
        scol[c] = s;
        qcol[c] = q;
    }
#pragma unroll
    for (int c = 0; c < 8; c++) {
        scol[c] += __shfl_xor(scol[c], 16);
        scol[c] += __shfl_xor(scol[c], 32);
        qcol[c] += __shfl_xor(qcol[c], 16);
        qcol[c] += __shfl_xor(qcol[c], 32);
    }
    __syncthreads();
    float* sStat = (float*)sA;
    if (lane < 16) {
#pragma unroll
        for (int c = 0; c < 8; c++) {
            sStat[w * 256 + c * 16 + lane] = scol[c];
            sStat[w * 256 + 128 + c * 16 + lane] = qcol[c];
        }
    }
    __syncthreads();
    if (t < 128) {
        float ss = sStat[t] + sStat[256 + t] + sStat[512 + t] + sStat[768 + t];
        float qq = sStat[128 + t] + sStat[384 + t] + sStat[640 + t] + sStat[896 + t];
        atomicAdd(&stats[t], ss);
        atomicAdd(&stats[128 + t], qq);
    }
}

// ---------------- final: BN(z2) -> per-graph mean pool -> dot --------------
__global__ __launch_bounds__(256) void k_finalpool(const bfp16* __restrict__ z2,
                                                   const float* __restrict__ stats,
                                                   const float* __restrict__ gamma,
                                                   const float* __restrict__ beta,
                                                   const int* __restrict__ batch,
                                                   const float* __restrict__ mol,
                                                   const float* __restrict__ Wf,
                                                   const float* __restrict__ bfp,
                                                   float* __restrict__ out) {
    int gid = (blockIdx.x * blockDim.x + threadIdx.x) >> 6;
    int lane = threadIdx.x & 63;
    if (gid >= NG) return;
    const int f = lane * 2;

    const float invn = 1.f / NN;
    float m0 = stats[f] * invn;
    float v0 = stats[128 + f] * invn - m0 * m0;
    float sc0 = rsqrtf(v0 + BN_EPS) * gamma[f];
    float sf0 = beta[f] - m0 * sc0;
    float m1 = stats[f + 1] * invn;
    float v1 = stats[128 + f + 1] * invn - m1 * m1;
    float sc1 = rsqrtf(v1 + BN_EPS) * gamma[f + 1];
    float sf1 = beta[f + 1] - m1 * sc1;

    int lo = 0, hi = NN;
    while (lo < hi) { int m = (lo + hi) >> 1; if (batch[m] < gid) lo = m + 1; else hi = m; }
    int lb = lo;
    hi = NN;
    while (lo < hi) { int m = (lo + hi) >> 1; if (batch[m] <= gid) lo = m + 1; else hi = m; }
    int cnt = lo - lb;

    float sx = 0.f, sy = 0.f;
    for (int n = lb; n < lo; n++) {
        float2 v = __bfloat1622float2(*(const bfp162*)&z2[(size_t)n * HID + f]);
        sx += fmaxf(v.x * sc0 + sf0, 0.f);
        sy += fmaxf(v.y * sc1 + sf1, 0.f);
    }
    float inv = 1.f / fmaxf((float)cnt, 1.f);
    float acc = sx * inv * Wf[f] + sy * inv * Wf[f + 1];
    if (lane < DESCD) acc += mol[(size_t)gid * DESCD + lane] * Wf[HID + lane];
#pragma unroll
    for (int o = 32; o > 0; o >>= 1) acc += __shfl_down(acc, o);
    if (lane == 0) out[gid] = acc + bfp[0];
}

extern "C" void kernel_launch(void* const* d_in, const int* in_sizes, int n_in,
                              void* d_out, int out_size, void* d_ws, size_t ws_size,
                              hipStream_t stream) {
    const float* x     = (const float*)d_in[0];
    const int*   ei    = (const int*)d_in[1];
    const float* ea    = (const float*)d_in[2];
    const int*   batch = (const int*)d_in[3];
    const float* mol   = (const float*)d_in[4];
    const float* Wp    = (const float*)d_in[5];
    const float* bp    = (const float*)d_in[6];
    const float* W1    = (const float*)d_in[7];
    const float* b1    = (const float*)d_in[8];
    const float* W2    = (const float*)d_in[9];
    const float* b2    = (const float*)d_in[10];
    const float* gamma = (const float*)d_in[11];
    const float* beta  = (const float*)d_in[12];
    const float* Wf    = (const float*)d_in[13];
    const float* bf_   = (const float*)d_in[14];
    float* out = (float*)d_out;

    char* p = (char*)d_ws;
    size_t off = 0;
    auto alloc = [&](size_t bytes) {
        char* q = p + off;
        off = (off + bytes + 255) & ~(size_t)255;
        return q;
    };
    bfp16* h      = (bfp16*)alloc((size_t)NN * HID * 2);
    bfp16* z      = (bfp16*)alloc((size_t)NN * HID * 2);
    bfp16* z2     = (bfp16*)alloc((size_t)NN * HID * 2);
    bfp16* Wt     = (bfp16*)alloc((size_t)6 * HID * HID * 2);
    int2*  perm   = (int2*)alloc((size_t)NE * 8);
    int*   rowptr = (int*)alloc((NN + 16) * 4);
    int*   cursor = (int*)alloc(NN * 4);
    int*   partials = (int*)alloc(NB_SCAN * 4);
    int*   poffs    = (int*)alloc(NB_SCAN * 4);
    // contiguous zero-init region: deg | stats3
    size_t zoff = off;
    int*   deg    = (int*)alloc(NN * 4);
    float* stats3 = (float*)alloc(3 * 256 * 4);
    size_t zlen = off - zoff;
    bfp16* eab    = (bfp16*)alloc((size_t)NE * HID * 2);

    const int* src = ei;
    const int* dst = ei + NE;

    (void)hipMemsetAsync(p + zoff, 0, zlen, stream);
    k_hist<<<(NE + 255) / 256, 256, 0, stream>>>(dst, deg);
    k_part<<<NB_SCAN, 256, 0, stream>>>(deg, partials);
    k_scanpart<<<1, 256, 0, stream>>>(partials, poffs);
    k_scatter<<<NB_SCAN, 256, 0, stream>>>(deg, poffs, rowptr, cursor);
    {
        const int fillBlocks = (NE + 255) / 256;
        const int projBlocks = (NN * HID) / 256;
        const int wprepBlocks = (6 * HID * HID + 255) / 256;
        k_fillproj<<<fillBlocks + projBlocks + wprepBlocks, 256, 0, stream>>>(
            src, dst, cursor, perm, x, Wp, bp, h, W1, W2, Wt,
            fillBlocks, projBlocks);
    }

    const int aggrGrid = (NN * 64) / 256;
    const int mlpGrid = (NN + 63) / 64;
    for (int l = 0; l < NL; l++) {
        if (l == 0)
            k_aggr<1, false><<<aggrGrid, 256, 0, stream>>>(
                h, ea, eab, perm, rowptr, nullptr, nullptr, nullptr, z);
        else
            k_aggr<2, true><<<aggrGrid, 256, 0, stream>>>(
                z2, nullptr, eab, perm, rowptr, stats3 + (l - 1) * 256,
                gamma + (l - 1) * HID, beta + (l - 1) * HID, z);
        k_mlp<<<mlpGrid, 256, 0, stream>>>(
            z, Wt + (size_t)l * HID * HID, Wt + (size_t)(3 + l) * HID * HID,
            b1 + l * HID, b2 + l * HID, z2, stats3 + l * 256, NN);
    }

    k_finalpool<<<(NG * 64) / 256, 256, 0, stream>>>(
        z2, stats3 + 2 * 256, gamma + 2 * HID, beta + 2 * HID,
        batch, mol, Wf, bf_, out);
}